// Round 1
// baseline (3028.440 us; speedup 1.0000x reference)
//
#include <hip/hip_runtime.h>

#define HID 128
#define NEG_SLOPE 0.01f
#define ROWS 32
#define PAD 36   // 32 rows + 4 pad: 36*4=144B row pitch -> 16B-aligned float4 reads, banks cycle

// ---------------- K0: transpose the three 128x128 weights: WT[k][h] = W[h][k]
__global__ __launch_bounds__(128) void k_transpose(
    const float* __restrict__ W1, const float* __restrict__ W2, const float* __restrict__ W3,
    float* __restrict__ WT)
{
    int m = blockIdx.x >> 7;   // 0..2
    int h = blockIdx.x & 127;
    int k = threadIdx.x;
    const float* W = (m == 0) ? W1 : (m == 1) ? W2 : W3;
    WT[(size_t)m * HID * HID + (size_t)k * HID + h] = W[(size_t)h * HID + k];
}

// ---------------- K1: X = primal @ W2^T - last_primal @ W3^T + (b2 - b3)
// block = 256 threads, tile = 32 rows x 128 cols, 4x4 per-thread register tile.
__global__ __launch_bounds__(256) void k_theta_x(
    const float* __restrict__ primal, const float* __restrict__ lastp,
    const float* __restrict__ W2T, const float* __restrict__ W3T,
    const float* __restrict__ b2, const float* __restrict__ b3,
    float* __restrict__ X)
{
    __shared__ __align__(16) float pT[HID][PAD];
    __shared__ __align__(16) float lT[HID][PAD];
    const int tid = threadIdx.x;
    const long base = (long)blockIdx.x * ROWS;

    // stage 32x128 tiles, transposed into LDS (coalesced global reads)
    #pragma unroll
    for (int i = 0; i < 16; ++i) {
        int idx = i * 256 + tid;
        int r = idx >> 7, k = idx & 127;
        pT[k][r] = primal[(base + r) * HID + k];
        lT[k][r] = lastp[(base + r) * HID + k];
    }
    __syncthreads();

    const int tc = tid & 31;   // cols h = tc + 32*j
    const int tr = tid >> 5;   // rows r = base + tr*4 + i
    float acc[4][4];
    #pragma unroll
    for (int j = 0; j < 4; ++j) {
        float bb = b2[tc + 32 * j] - b3[tc + 32 * j];
        acc[0][j] = bb; acc[1][j] = bb; acc[2][j] = bb; acc[3][j] = bb;
    }

    #pragma unroll 4
    for (int k = 0; k < HID; ++k) {
        float4 a4 = *(const float4*)&pT[k][tr * 4];   // broadcast within half-wave
        float4 l4 = *(const float4*)&lT[k][tr * 4];
        float w2[4], w3[4];
        #pragma unroll
        for (int j = 0; j < 4; ++j) {
            w2[j] = W2T[k * HID + tc + 32 * j];       // 128B coalesced segments, L1/L2 resident
            w3[j] = W3T[k * HID + tc + 32 * j];
        }
        float a[4] = {a4.x, a4.y, a4.z, a4.w};
        float l[4] = {l4.x, l4.y, l4.z, l4.w};
        #pragma unroll
        for (int i = 0; i < 4; ++i)
            #pragma unroll
            for (int j = 0; j < 4; ++j)
                acc[i][j] += a[i] * w2[j] - l[i] * w3[j];
    }

    #pragma unroll
    for (int i = 0; i < 4; ++i) {
        long r = base + tr * 4 + i;
        #pragma unroll
        for (int j = 0; j < 4; ++j)
            X[r * HID + tc + 32 * j] = acc[i][j];
    }
}

// ---------------- K2: scatter-add sigma*vals[e]*X[cols[e],:] into out[rows[e],:]
// one thread per (nnz, 32-lane group); float4 gather + 4 atomics
__global__ __launch_bounds__(256) void k_scatter(
    const int* __restrict__ rows, const int* __restrict__ cols, const float* __restrict__ vals,
    const float* __restrict__ X, const float* __restrict__ sigp, float* __restrict__ out,
    int nnz)
{
    const float sigma = *sigp;
    long gid = (long)blockIdx.x * 256 + threadIdx.x;
    long e = gid >> 5;
    if (e >= nnz) return;
    int lane = (int)(gid & 31);
    int c = cols[e];
    int r = rows[e];
    float sv = sigma * vals[e];
    const float4 x = *(const float4*)&X[(long)c * HID + lane * 4];
    float* dst = out + (long)r * HID + lane * 4;
    atomicAdd(dst + 0, sv * x.x);
    atomicAdd(dst + 1, sv * x.y);
    atomicAdd(dst + 2, sv * x.z);
    atomicAdd(dst + 3, sv * x.w);
}

// ---------------- K3: out = leaky_relu(dual @ W1^T + b1 + out - sigma*rhs)
// (out currently holds sigma*AX from the scatter)
__global__ __launch_bounds__(256) void k_dual_out(
    const float* __restrict__ dual, const float* __restrict__ W1T, const float* __restrict__ b1,
    const float* __restrict__ rhs, const float* __restrict__ sigp, float* __restrict__ out)
{
    __shared__ __align__(16) float dT[HID][PAD];
    const float sigma = *sigp;
    const int tid = threadIdx.x;
    const long base = (long)blockIdx.x * ROWS;

    #pragma unroll
    for (int i = 0; i < 16; ++i) {
        int idx = i * 256 + tid;
        int r = idx >> 7, k = idx & 127;
        dT[k][r] = dual[(base + r) * HID + k];
    }
    __syncthreads();

    const int tc = tid & 31;
    const int tr = tid >> 5;
    float acc[4][4];
    #pragma unroll
    for (int j = 0; j < 4; ++j) {
        float bb = b1[tc + 32 * j];
        acc[0][j] = bb; acc[1][j] = bb; acc[2][j] = bb; acc[3][j] = bb;
    }

    #pragma unroll 4
    for (int k = 0; k < HID; ++k) {
        float4 a4 = *(const float4*)&dT[k][tr * 4];
        float w1[4];
        #pragma unroll
        for (int j = 0; j < 4; ++j)
            w1[j] = W1T[k * HID + tc + 32 * j];
        float a[4] = {a4.x, a4.y, a4.z, a4.w};
        #pragma unroll
        for (int i = 0; i < 4; ++i)
            #pragma unroll
            for (int j = 0; j < 4; ++j)
                acc[i][j] += a[i] * w1[j];
    }

    #pragma unroll
    for (int i = 0; i < 4; ++i) {
        long r = base + tr * 4 + i;
        #pragma unroll
        for (int j = 0; j < 4; ++j) {
            long idx = r * HID + tc + 32 * j;
            float pre = acc[i][j] + out[idx] - sigma * rhs[idx];
            out[idx] = (pre >= 0.0f) ? pre : NEG_SLOPE * pre;
        }
    }
}

extern "C" void kernel_launch(void* const* d_in, const int* in_sizes, int n_in,
                              void* d_out, int out_size, void* d_ws, size_t ws_size,
                              hipStream_t stream) {
    const float* primal = (const float*)d_in[0];
    const float* lastp  = (const float*)d_in[1];
    const float* dual   = (const float*)d_in[2];
    const int*   rows   = (const int*)d_in[3];
    const int*   cols   = (const int*)d_in[4];
    const float* vals   = (const float*)d_in[5];
    const float* rhs    = (const float*)d_in[6];
    const float* W1     = (const float*)d_in[7];
    const float* b1     = (const float*)d_in[8];
    const float* W2     = (const float*)d_in[9];
    const float* b2     = (const float*)d_in[10];
    const float* W3     = (const float*)d_in[11];
    const float* b3     = (const float*)d_in[12];
    const float* sigp   = (const float*)d_in[13];

    const int nvars = in_sizes[0] / HID;   // 200000
    const int mcons = in_sizes[2] / HID;   // 100000
    const int nnz   = in_sizes[3];         // 1600000

    float* out = (float*)d_out;
    float* X   = (float*)d_ws;                         // nvars*128 f32 = 102.4 MB
    float* WT  = X + (size_t)nvars * HID;              // 3 * 128*128 f32
    float* W1T = WT;
    float* W2T = WT + HID * HID;
    float* W3T = WT + 2 * HID * HID;

    // out accumulates sigma*AX, so zero it first (harness does not re-poison between replays)
    hipMemsetAsync(d_out, 0, (size_t)out_size * sizeof(float), stream);

    k_transpose<<<3 * HID, HID, 0, stream>>>(W1, W2, W3, WT);

    k_theta_x<<<nvars / ROWS, 256, 0, stream>>>(primal, lastp, W2T, W3T, b2, b3, X);

    long total = (long)nnz * 32;
    k_scatter<<<(int)((total + 255) / 256), 256, 0, stream>>>(rows, cols, vals, X, sigp, out, nnz);

    k_dual_out<<<mcons / ROWS, 256, 0, stream>>>(dual, W1T, b1, rhs, sigp, out);
}

// Round 2
// 700.010 us; speedup vs baseline: 4.3263x; 4.3263x over previous
//
#include <hip/hip_runtime.h>

#define HID 128
#define NEG_SLOPE 0.01f
#define ROWS 32
#define PAD 36   // 32 rows + 4 pad: 144B row pitch -> aligned float4, banks cycle

// ---------------- K0: transpose the three 128x128 weights: WT[k][h] = W[h][k]
__global__ __launch_bounds__(128) void k_transpose(
    const float* __restrict__ W1, const float* __restrict__ W2, const float* __restrict__ W3,
    float* __restrict__ WT)
{
    int m = blockIdx.x >> 7;   // 0..2
    int h = blockIdx.x & 127;
    int k = threadIdx.x;
    const float* W = (m == 0) ? W1 : (m == 1) ? W2 : W3;
    WT[(size_t)m * HID * HID + (size_t)k * HID + h] = W[(size_t)h * HID + k];
}

// ---------------- K1: X = primal @ W2^T - last_primal @ W3^T + (b2 - b3)
__global__ __launch_bounds__(256) void k_theta_x(
    const float* __restrict__ primal, const float* __restrict__ lastp,
    const float* __restrict__ W2T, const float* __restrict__ W3T,
    const float* __restrict__ b2, const float* __restrict__ b3,
    float* __restrict__ X)
{
    __shared__ __align__(16) float pT[HID][PAD];
    __shared__ __align__(16) float lT[HID][PAD];
    const int tid = threadIdx.x;
    const long base = (long)blockIdx.x * ROWS;

    #pragma unroll
    for (int i = 0; i < 16; ++i) {
        int idx = i * 256 + tid;
        int r = idx >> 7, k = idx & 127;
        pT[k][r] = primal[(base + r) * HID + k];
        lT[k][r] = lastp[(base + r) * HID + k];
    }
    __syncthreads();

    const int tc = tid & 31;
    const int tr = tid >> 5;
    float acc[4][4];
    #pragma unroll
    for (int j = 0; j < 4; ++j) {
        float bb = b2[tc + 32 * j] - b3[tc + 32 * j];
        acc[0][j] = bb; acc[1][j] = bb; acc[2][j] = bb; acc[3][j] = bb;
    }

    #pragma unroll 4
    for (int k = 0; k < HID; ++k) {
        float4 a4 = *(const float4*)&pT[k][tr * 4];
        float4 l4 = *(const float4*)&lT[k][tr * 4];
        float w2[4], w3[4];
        #pragma unroll
        for (int j = 0; j < 4; ++j) {
            w2[j] = W2T[k * HID + tc + 32 * j];
            w3[j] = W3T[k * HID + tc + 32 * j];
        }
        float a[4] = {a4.x, a4.y, a4.z, a4.w};
        float l[4] = {l4.x, l4.y, l4.z, l4.w};
        #pragma unroll
        for (int i = 0; i < 4; ++i)
            #pragma unroll
            for (int j = 0; j < 4; ++j)
                acc[i][j] += a[i] * w2[j] - l[i] * w3[j];
    }

    #pragma unroll
    for (int i = 0; i < 4; ++i) {
        long r = base + tr * 4 + i;
        #pragma unroll
        for (int j = 0; j < 4; ++j)
            X[r * HID + tc + 32 * j] = acc[i][j];
    }
}

// ---------------- CSR build ----------------
// K2a: histogram of rows
__global__ __launch_bounds__(256) void k_count(
    const int* __restrict__ rows, int* __restrict__ count, int nnz)
{
    int e = blockIdx.x * 256 + threadIdx.x;
    if (e < nnz) atomicAdd(&count[rows[e]], 1);
}

// K2b: per-chunk sums (chunk = 1024 elements, 256 threads x 4)
__global__ __launch_bounds__(256) void k_scan1(
    const int* __restrict__ count, int* __restrict__ bsum, int m)
{
    __shared__ int red[256];
    int b = blockIdx.x, t = threadIdx.x;
    int base = b * 1024 + t * 4;
    int s = 0;
    #pragma unroll
    for (int i = 0; i < 4; ++i) { int idx = base + i; if (idx < m) s += count[idx]; }
    red[t] = s; __syncthreads();
    for (int off = 128; off > 0; off >>= 1) {
        if (t < off) red[t] += red[t + off];
        __syncthreads();
    }
    if (t == 0) bsum[b] = red[0];
}

// K2c: exclusive scan of chunk sums (single thread; nchunks ~ 98)
__global__ void k_scan2(const int* __restrict__ bsum, int* __restrict__ boff, int nchunks)
{
    if (threadIdx.x == 0 && blockIdx.x == 0) {
        int run = 0;
        for (int i = 0; i < nchunks; ++i) { boff[i] = run; run += bsum[i]; }
    }
}

// K2d: in-chunk exclusive scan + offset -> rowstart, cursor
__global__ __launch_bounds__(256) void k_scan3(
    const int* __restrict__ count, const int* __restrict__ boff,
    int* __restrict__ rowstart, int* __restrict__ cursor, int m)
{
    __shared__ int tsum[256];
    int b = blockIdx.x, t = threadIdx.x;
    int base = b * 1024 + t * 4;
    int v[4]; int s = 0;
    #pragma unroll
    for (int i = 0; i < 4; ++i) { int idx = base + i; v[i] = (idx < m) ? count[idx] : 0; s += v[i]; }
    tsum[t] = s; __syncthreads();
    // Hillis-Steele inclusive scan over 256 thread sums
    for (int off = 1; off < 256; off <<= 1) {
        int x = (t >= off) ? tsum[t - off] : 0;
        __syncthreads();
        tsum[t] += x;
        __syncthreads();
    }
    int run = tsum[t] - s + boff[b];   // exclusive prefix for this thread
    #pragma unroll
    for (int i = 0; i < 4; ++i) {
        int idx = base + i;
        if (idx < m) { rowstart[idx] = run; cursor[idx] = run; run += v[i]; }
    }
}

// K2e: permute (col,val) pairs into CSR order
__global__ __launch_bounds__(256) void k_fill(
    const int* __restrict__ rows, const int* __restrict__ cols, const float* __restrict__ vals,
    int* __restrict__ cursor, int2* __restrict__ pairs, int nnz)
{
    int e = blockIdx.x * 256 + threadIdx.x;
    if (e >= nnz) return;
    int r = rows[e];
    int slot = atomicAdd(&cursor[r], 1);
    int2 p; p.x = cols[e]; p.y = __float_as_int(vals[e]);
    pairs[slot] = p;
}

// ---------------- K3: segment sum: out[r,:] = sigma * sum_j val_j * X[col_j,:]
// one 64-lane wave per row; float2 per lane = 128 cols
__global__ __launch_bounds__(256) void k_segsum(
    const int2* __restrict__ pairs, const int* __restrict__ rowstart, const int* __restrict__ count,
    const float* __restrict__ X, const float* __restrict__ sigp, float* __restrict__ out, int m)
{
    int wid = (blockIdx.x * 256 + threadIdx.x) >> 6;
    if (wid >= m) return;
    int lane = threadIdx.x & 63;
    int start = rowstart[wid];
    int cnt   = count[wid];
    float2 acc = make_float2(0.f, 0.f);
    for (int j = 0; j < cnt; ++j) {
        int2 p = pairs[start + j];                       // wave-uniform 8B load
        float v = __int_as_float(p.y);
        const float2 x = *(const float2*)&X[(size_t)p.x * HID + lane * 2];
        acc.x += v * x.x;
        acc.y += v * x.y;
    }
    float sg = *sigp;
    ((float2*)out)[(size_t)wid * 64 + lane] = make_float2(sg * acc.x, sg * acc.y);
}

// ---------------- K4: out = leaky_relu(dual @ W1^T + b1 + out - sigma*rhs)
__global__ __launch_bounds__(256) void k_dual_out(
    const float* __restrict__ dual, const float* __restrict__ W1T, const float* __restrict__ b1,
    const float* __restrict__ rhs, const float* __restrict__ sigp, float* __restrict__ out)
{
    __shared__ __align__(16) float dT[HID][PAD];
    const float sigma = *sigp;
    const int tid = threadIdx.x;
    const long base = (long)blockIdx.x * ROWS;

    #pragma unroll
    for (int i = 0; i < 16; ++i) {
        int idx = i * 256 + tid;
        int r = idx >> 7, k = idx & 127;
        dT[k][r] = dual[(base + r) * HID + k];
    }
    __syncthreads();

    const int tc = tid & 31;
    const int tr = tid >> 5;
    float acc[4][4];
    #pragma unroll
    for (int j = 0; j < 4; ++j) {
        float bb = b1[tc + 32 * j];
        acc[0][j] = bb; acc[1][j] = bb; acc[2][j] = bb; acc[3][j] = bb;
    }

    #pragma unroll 4
    for (int k = 0; k < HID; ++k) {
        float4 a4 = *(const float4*)&dT[k][tr * 4];
        float w1[4];
        #pragma unroll
        for (int j = 0; j < 4; ++j)
            w1[j] = W1T[k * HID + tc + 32 * j];
        float a[4] = {a4.x, a4.y, a4.z, a4.w};
        #pragma unroll
        for (int i = 0; i < 4; ++i)
            #pragma unroll
            for (int j = 0; j < 4; ++j)
                acc[i][j] += a[i] * w1[j];
    }

    #pragma unroll
    for (int i = 0; i < 4; ++i) {
        long r = base + tr * 4 + i;
        #pragma unroll
        for (int j = 0; j < 4; ++j) {
            long idx = r * HID + tc + 32 * j;
            float pre = acc[i][j] + out[idx] - sigma * rhs[idx];
            out[idx] = (pre >= 0.0f) ? pre : NEG_SLOPE * pre;
        }
    }
}

extern "C" void kernel_launch(void* const* d_in, const int* in_sizes, int n_in,
                              void* d_out, int out_size, void* d_ws, size_t ws_size,
                              hipStream_t stream) {
    const float* primal = (const float*)d_in[0];
    const float* lastp  = (const float*)d_in[1];
    const float* dual   = (const float*)d_in[2];
    const int*   rows   = (const int*)d_in[3];
    const int*   cols   = (const int*)d_in[4];
    const float* vals   = (const float*)d_in[5];
    const float* rhs    = (const float*)d_in[6];
    const float* W1     = (const float*)d_in[7];
    const float* b1     = (const float*)d_in[8];
    const float* W2     = (const float*)d_in[9];
    const float* b2     = (const float*)d_in[10];
    const float* W3     = (const float*)d_in[11];
    const float* b3     = (const float*)d_in[12];
    const float* sigp   = (const float*)d_in[13];

    const int nvars = in_sizes[0] / HID;   // 200000
    const int mcons = in_sizes[2] / HID;   // 100000
    const int nnz   = in_sizes[3];         // 1600000

    float* out = (float*)d_out;

    // ---- workspace layout (bytes) ----
    char* wsb = (char*)d_ws;
    float* X        = (float*)wsb;                               // nvars*128 f32 = 102.4 MB
    size_t off      = (size_t)nvars * HID * sizeof(float);
    int2*  pairs    = (int2*)(wsb + off);  off += (size_t)nnz * sizeof(int2);     // 12.8 MB
    float* WT       = (float*)(wsb + off); off += 3 * HID * HID * sizeof(float);  // 192 KB
    int*   count    = (int*)(wsb + off);   off += (size_t)mcons * sizeof(int);
    int*   rowstart = (int*)(wsb + off);   off += (size_t)mcons * sizeof(int);
    int*   cursor   = (int*)(wsb + off);   off += (size_t)mcons * sizeof(int);
    int*   bsum     = (int*)(wsb + off);   off += 1024 * sizeof(int);
    int*   boff     = (int*)(wsb + off);   off += 1024 * sizeof(int);
    float* W1T = WT;
    float* W2T = WT + HID * HID;
    float* W3T = WT + 2 * HID * HID;

    const int nchunks = (mcons + 1023) / 1024;

    hipMemsetAsync(count, 0, (size_t)mcons * sizeof(int), stream);

    k_transpose<<<3 * HID, HID, 0, stream>>>(W1, W2, W3, WT);

    k_theta_x<<<nvars / ROWS, 256, 0, stream>>>(primal, lastp, W2T, W3T, b2, b3, X);

    // CSR build (overlaps nothing, but each stage is tiny)
    k_count<<<(nnz + 255) / 256, 256, 0, stream>>>(rows, count, nnz);
    k_scan1<<<nchunks, 256, 0, stream>>>(count, bsum, mcons);
    k_scan2<<<1, 64, 0, stream>>>(bsum, boff, nchunks);
    k_scan3<<<nchunks, 256, 0, stream>>>(count, boff, rowstart, cursor, mcons);
    k_fill<<<(nnz + 255) / 256, 256, 0, stream>>>(rows, cols, vals, cursor, pairs, nnz);

    k_segsum<<<(mcons * 64 + 255) / 256, 256, 0, stream>>>(pairs, rowstart, count, X, sigp, out, mcons);

    k_dual_out<<<mcons / ROWS, 256, 0, stream>>>(dual, W1T, b1, rhs, sigp, out);
}

// Round 4
// 481.420 us; speedup vs baseline: 6.2906x; 1.4541x over previous
//
#include <hip/hip_runtime.h>

#define HID 128
#define NEG_SLOPE 0.01f

typedef __attribute__((ext_vector_type(8))) short short8;
typedef __attribute__((ext_vector_type(4))) float f32x4;

__device__ inline unsigned short f2bfu(float f) {
    unsigned u = __float_as_uint(f);
    u += 0x7fff + ((u >> 16) & 1);          // round-to-nearest-even
    return (unsigned short)(u >> 16);
}
__device__ inline float bf2f_lo(unsigned x) { return __uint_as_float((x & 0xffffu) << 16); }
__device__ inline float bf2f_hi(unsigned x) { return __uint_as_float(x & 0xffff0000u); }

#define MFMA16(accv, av, bv) \
    asm("v_mfma_f32_16x16x32_bf16 %0, %1, %2, %0" : "+v"(accv) : "v"(av), "v"(bv))

// ---------------- K0: pack weights to bf16. Wcat[n][k] = bf16(k<128 ? W2[n][k] : -W3[n][k-128]);
// W1b[n][k] = bf16(W1[n][k]).  Both in B^T ([N][K]) layout = the original torch layout.
__global__ __launch_bounds__(256) void k_prep(
    const float* __restrict__ W1, const float* __restrict__ W2, const float* __restrict__ W3,
    unsigned short* __restrict__ Wcat, unsigned short* __restrict__ W1b)
{
    int gid = blockIdx.x * 256 + threadIdx.x;
    if (gid < 128 * 256) {
        int n = gid >> 8, k = gid & 255;
        float v = (k < 128) ? W2[n * 128 + k] : -W3[n * 128 + (k - 128)];
        Wcat[gid] = f2bfu(v);
    } else {
        int g = gid - 128 * 256;
        W1b[g] = f2bfu(W1[g]);
    }
}

// ---------------- K1: Xb = bf16( [primal|lastp] @ Wcat^T + (b2-b3) )
// block 256 = 4 waves; M-tile 128 (32 rows/wave as 2 groups of 16), N = 128, K = 256 (2 halves).
__global__ __launch_bounds__(256) void k_theta_mfma(
    const float* __restrict__ primal, const float* __restrict__ lastp,
    const short8* __restrict__ Wcat,          // [128][256] bf16 = [128][32] short8
    const float* __restrict__ b2, const float* __restrict__ b3,
    unsigned short* __restrict__ Xb, int nvars)
{
    __shared__ short8 Blds[2048];             // 32 KB: one K-half in fragment order
    const int t = threadIdx.x;
    const int l = t & 63, wv = t >> 6;
    const long mbase = (long)blockIdx.x * 128;

    const f32x4 z = {0.f, 0.f, 0.f, 0.f};
    f32x4 acc[2][8];
    #pragma unroll
    for (int rg = 0; rg < 2; ++rg)
        #pragma unroll
        for (int nb = 0; nb < 8; ++nb) acc[rg][nb] = z;

    for (int half = 0; half < 2; ++half) {
        if (half) __syncthreads();            // finish reads of previous half
        // stage B-half into LDS, pre-arranged in fragment order: entry (nb,ks,lane)
        #pragma unroll
        for (int i = 0; i < 8; ++i) {
            int e = t + i * 256;
            int lane = e & 63, ks = (e >> 6) & 3, nb = e >> 8;
            int row = nb * 16 + (lane & 15);
            int col8 = (half * 128 + ks * 32 + ((lane >> 4) << 3)) >> 3;
            Blds[e] = Wcat[row * 32 + col8];
        }
        __syncthreads();

        const float* Ap = half ? lastp : primal;
        for (int ks = 0; ks < 4; ++ks) {
            short8 af[2];
            #pragma unroll
            for (int rg = 0; rg < 2; ++rg) {
                long row = mbase + wv * 32 + rg * 16 + (l & 15);
                float4 x0 = {0, 0, 0, 0}, x1 = {0, 0, 0, 0};
                if (row < nvars) {
                    const float4* s = (const float4*)(Ap + row * HID + ks * 32 + ((l >> 4) << 3));
                    x0 = s[0]; x1 = s[1];
                }
                af[rg][0] = (short)f2bfu(x0.x); af[rg][1] = (short)f2bfu(x0.y);
                af[rg][2] = (short)f2bfu(x0.z); af[rg][3] = (short)f2bfu(x0.w);
                af[rg][4] = (short)f2bfu(x1.x); af[rg][5] = (short)f2bfu(x1.y);
                af[rg][6] = (short)f2bfu(x1.z); af[rg][7] = (short)f2bfu(x1.w);
            }
            #pragma unroll
            for (int nb = 0; nb < 8; ++nb) {
                short8 bv = Blds[(nb * 4 + ks) * 64 + l];
                MFMA16(acc[0][nb], af[0], bv);
                MFMA16(acc[1][nb], af[1], bv);
            }
        }
    }
    asm volatile("s_nop 7\ns_nop 7");          // MFMA->VALU read hazard insurance

    // epilogue: add bias, convert to bf16, store. C/D: col = l&15, row = (l>>4)*4 + q  [m89/m91]
    #pragma unroll
    for (int nb = 0; nb < 8; ++nb) {
        int col = nb * 16 + (l & 15);
        float bb = b2[col] - b3[col];
        #pragma unroll
        for (int rg = 0; rg < 2; ++rg) {
            #pragma unroll
            for (int q = 0; q < 4; ++q) {
                long row = mbase + wv * 32 + rg * 16 + ((l >> 4) * 4 + q);
                if (row < nvars) Xb[row * HID + col] = f2bfu(acc[rg][nb][q] + bb);
            }
        }
    }
}

// ---------------- CSR build ----------------
__global__ __launch_bounds__(256) void k_count(
    const int* __restrict__ rows, int* __restrict__ count, int nnz)
{
    int e = blockIdx.x * 256 + threadIdx.x;
    if (e < nnz) atomicAdd(&count[rows[e]], 1);
}

__global__ __launch_bounds__(256) void k_scan1(
    const int* __restrict__ count, int* __restrict__ bsum, int m)
{
    __shared__ int red[256];
    int b = blockIdx.x, t = threadIdx.x;
    int base = b * 1024 + t * 4;
    int s = 0;
    #pragma unroll
    for (int i = 0; i < 4; ++i) { int idx = base + i; if (idx < m) s += count[idx]; }
    red[t] = s; __syncthreads();
    for (int off = 128; off > 0; off >>= 1) {
        if (t < off) red[t] += red[t + off];
        __syncthreads();
    }
    if (t == 0) bsum[b] = red[0];
}

__global__ void k_scan2(const int* __restrict__ bsum, int* __restrict__ boff, int nchunks)
{
    if (threadIdx.x == 0 && blockIdx.x == 0) {
        int run = 0;
        for (int i = 0; i < nchunks; ++i) { boff[i] = run; run += bsum[i]; }
    }
}

__global__ __launch_bounds__(256) void k_scan3(
    const int* __restrict__ count, const int* __restrict__ boff,
    int* __restrict__ rowstart, int* __restrict__ cursor, int m)
{
    __shared__ int tsum[256];
    int b = blockIdx.x, t = threadIdx.x;
    int base = b * 1024 + t * 4;
    int v[4]; int s = 0;
    #pragma unroll
    for (int i = 0; i < 4; ++i) { int idx = base + i; v[i] = (idx < m) ? count[idx] : 0; s += v[i]; }
    tsum[t] = s; __syncthreads();
    for (int off = 1; off < 256; off <<= 1) {
        int x = (t >= off) ? tsum[t - off] : 0;
        __syncthreads();
        tsum[t] += x;
        __syncthreads();
    }
    int run = tsum[t] - s + boff[b];
    #pragma unroll
    for (int i = 0; i < 4; ++i) {
        int idx = base + i;
        if (idx < m) { rowstart[idx] = run; cursor[idx] = run; run += v[i]; }
    }
}

__global__ __launch_bounds__(256) void k_fill(
    const int* __restrict__ rows, const int* __restrict__ cols, const float* __restrict__ vals,
    int* __restrict__ cursor, int2* __restrict__ pairs, int nnz)
{
    int e = blockIdx.x * 256 + threadIdx.x;
    if (e >= nnz) return;
    int r = rows[e];
    int slot = atomicAdd(&cursor[r], 1);
    int2 p; p.x = cols[e]; p.y = __float_as_int(vals[e]);
    pairs[slot] = p;
}

// ---------------- K3: out[r,:] = sigma * sum_j val_j * X[col_j,:]   (one wave per row)
__global__ __launch_bounds__(256) void k_segsum(
    const int2* __restrict__ pairs, const int* __restrict__ rowstart, const int* __restrict__ count,
    const unsigned short* __restrict__ Xb, const float* __restrict__ sigp,
    float* __restrict__ out, int m)
{
    int wid = (blockIdx.x * 256 + threadIdx.x) >> 6;
    if (wid >= m) return;
    int lane = threadIdx.x & 63;
    int start = rowstart[wid];
    int cnt   = count[wid];
    float a0 = 0.f, a1 = 0.f;
    for (int j = 0; j < cnt; ++j) {
        int2 p = pairs[start + j];                       // wave-uniform 8B load
        float v = __int_as_float(p.y);
        unsigned x = *(const unsigned*)&Xb[(size_t)p.x * HID + lane * 2];
        a0 += v * bf2f_lo(x);
        a1 += v * bf2f_hi(x);
    }
    float sg = *sigp;
    ((float2*)out)[(size_t)wid * 64 + lane] = make_float2(sg * a0, sg * a1);
}

// ---------------- K4: out = leaky_relu(dual @ W1^T + b1 + out - sigma*rhs)   (out holds sigma*AX)
__global__ __launch_bounds__(256) void k_dual_mfma(
    const float* __restrict__ dual,
    const short8* __restrict__ W1b,           // [128][128] bf16 = [128][16] short8
    const float* __restrict__ b1, const float* __restrict__ rhs,
    const float* __restrict__ sigp, float* __restrict__ out, int mcons)
{
    __shared__ short8 Blds[2048];             // full W1: 2048 short8 = 128x128 bf16
    const int t = threadIdx.x;
    const int l = t & 63, wv = t >> 6;
    const long mbase = (long)blockIdx.x * 128;
    const float sigma = *sigp;

    const f32x4 z = {0.f, 0.f, 0.f, 0.f};
    f32x4 acc[2][8];
    #pragma unroll
    for (int rg = 0; rg < 2; ++rg)
        #pragma unroll
        for (int nb = 0; nb < 8; ++nb) acc[rg][nb] = z;

    // stage W1 (K=128): ALL 2048 entries (nb<8, ks<4, lane<64)  [R3 bug: was i<4]
    #pragma unroll
    for (int i = 0; i < 8; ++i) {
        int e = t + i * 256;
        int lane = e & 63, ks = (e >> 6) & 3, nb = e >> 8;
        int row = nb * 16 + (lane & 15);
        int col8 = (ks * 32 + ((lane >> 4) << 3)) >> 3;
        Blds[e] = W1b[row * 16 + col8];
    }
    __syncthreads();

    for (int ks = 0; ks < 4; ++ks) {
        short8 af[2];
        #pragma unroll
        for (int rg = 0; rg < 2; ++rg) {
            long row = mbase + wv * 32 + rg * 16 + (l & 15);
            float4 x0 = {0, 0, 0, 0}, x1 = {0, 0, 0, 0};
            if (row < mcons) {
                const float4* s = (const float4*)(dual + row * HID + ks * 32 + ((l >> 4) << 3));
                x0 = s[0]; x1 = s[1];
            }
            af[rg][0] = (short)f2bfu(x0.x); af[rg][1] = (short)f2bfu(x0.y);
            af[rg][2] = (short)f2bfu(x0.z); af[rg][3] = (short)f2bfu(x0.w);
            af[rg][4] = (short)f2bfu(x1.x); af[rg][5] = (short)f2bfu(x1.y);
            af[rg][6] = (short)f2bfu(x1.z); af[rg][7] = (short)f2bfu(x1.w);
        }
        #pragma unroll
        for (int nb = 0; nb < 8; ++nb) {
            short8 bv = Blds[(nb * 4 + ks) * 64 + l];
            MFMA16(acc[0][nb], af[0], bv);
            MFMA16(acc[1][nb], af[1], bv);
        }
    }
    asm volatile("s_nop 7\ns_nop 7");          // MFMA->VALU read hazard insurance

    #pragma unroll
    for (int nb = 0; nb < 8; ++nb) {
        int col = nb * 16 + (l & 15);
        float bb = b1[col];
        #pragma unroll
        for (int rg = 0; rg < 2; ++rg) {
            #pragma unroll
            for (int q = 0; q < 4; ++q) {
                long row = mbase + wv * 32 + rg * 16 + ((l >> 4) * 4 + q);
                if (row < mcons) {
                    long idx = row * HID + col;
                    float pre = acc[rg][nb][q] + bb + out[idx] - sigma * rhs[idx];
                    out[idx] = (pre >= 0.f) ? pre : NEG_SLOPE * pre;
                }
            }
        }
    }
}

extern "C" void kernel_launch(void* const* d_in, const int* in_sizes, int n_in,
                              void* d_out, int out_size, void* d_ws, size_t ws_size,
                              hipStream_t stream) {
    const float* primal = (const float*)d_in[0];
    const float* lastp  = (const float*)d_in[1];
    const float* dual   = (const float*)d_in[2];
    const int*   rows   = (const int*)d_in[3];
    const int*   cols   = (const int*)d_in[4];
    const float* vals   = (const float*)d_in[5];
    const float* rhs    = (const float*)d_in[6];
    const float* W1     = (const float*)d_in[7];
    const float* b1     = (const float*)d_in[8];
    const float* W2     = (const float*)d_in[9];
    const float* b2     = (const float*)d_in[10];
    const float* W3     = (const float*)d_in[11];
    const float* b3     = (const float*)d_in[12];
    const float* sigp   = (const float*)d_in[13];

    const int nvars = in_sizes[0] / HID;   // 200000
    const int mcons = in_sizes[2] / HID;   // 100000
    const int nnz   = in_sizes[3];         // 1600000

    float* out = (float*)d_out;

    // ---- workspace layout ----
    char* wsb = (char*)d_ws;
    unsigned short* Xb   = (unsigned short*)wsb;                       // 51.2 MB bf16
    size_t off = (size_t)nvars * HID * sizeof(unsigned short);
    int2* pairs          = (int2*)(wsb + off); off += (size_t)nnz * sizeof(int2);   // 12.8 MB
    unsigned short* Wcat = (unsigned short*)(wsb + off); off += 128 * 256 * 2;
    unsigned short* W1b  = (unsigned short*)(wsb + off); off += 128 * 128 * 2;
    int* count    = (int*)(wsb + off); off += (size_t)mcons * sizeof(int);
    int* rowstart = (int*)(wsb + off); off += (size_t)mcons * sizeof(int);
    int* cursor   = (int*)(wsb + off); off += (size_t)mcons * sizeof(int);
    int* bsum     = (int*)(wsb + off); off += 1024 * sizeof(int);
    int* boff     = (int*)(wsb + off); off += 1024 * sizeof(int);

    const int nchunks = (mcons + 1023) / 1024;

    hipMemsetAsync(count, 0, (size_t)mcons * sizeof(int), stream);

    k_prep<<<192, 256, 0, stream>>>(W1, W2, W3, Wcat, W1b);

    k_theta_mfma<<<(nvars + 127) / 128, 256, 0, stream>>>(
        primal, lastp, (const short8*)Wcat, b2, b3, Xb, nvars);

    k_count<<<(nnz + 255) / 256, 256, 0, stream>>>(rows, count, nnz);
    k_scan1<<<nchunks, 256, 0, stream>>>(count, bsum, mcons);
    k_scan2<<<1, 64, 0, stream>>>(bsum, boff, nchunks);
    k_scan3<<<nchunks, 256, 0, stream>>>(count, boff, rowstart, cursor, mcons);
    k_fill<<<(nnz + 255) / 256, 256, 0, stream>>>(rows, cols, vals, cursor, pairs, nnz);

    k_segsum<<<(mcons * 64 + 255) / 256, 256, 0, stream>>>(
        pairs, rowstart, count, Xb, sigp, out, mcons);

    k_dual_mfma<<<(mcons + 127) / 128, 256, 0, stream>>>(
        dual, (const short8*)W1b, b1, rhs, sigp, out, mcons);
}

// Round 5
// 402.919 us; speedup vs baseline: 7.5162x; 1.1948x over previous
//
#include <hip/hip_runtime.h>

#define HID 128
#define NEG_SLOPE 0.01f

typedef __attribute__((ext_vector_type(8))) short short8;
typedef __attribute__((ext_vector_type(4))) float f32x4;

__device__ inline unsigned short f2bfu(float f) {
    unsigned u = __float_as_uint(f);
    u += 0x7fff + ((u >> 16) & 1);          // round-to-nearest-even
    return (unsigned short)(u >> 16);
}
__device__ inline float bf2f_lo(unsigned x) { return __uint_as_float((x & 0xffffu) << 16); }
__device__ inline float bf2f_hi(unsigned x) { return __uint_as_float(x & 0xffff0000u); }

#define MFMA16(accv, av, bv) \
    asm("v_mfma_f32_16x16x32_bf16 %0, %1, %2, %0" : "+v"(accv) : "v"(av), "v"(bv))

// ---------------- K0: pack weights to bf16. Wcat[n][k] = bf16(k<128 ? W2[n][k] : -W3[n][k-128]);
// W1b[n][k] = bf16(W1[n][k]).  Both in B^T ([N][K]) layout = the original torch layout.
__global__ __launch_bounds__(256) void k_prep(
    const float* __restrict__ W1, const float* __restrict__ W2, const float* __restrict__ W3,
    unsigned short* __restrict__ Wcat, unsigned short* __restrict__ W1b)
{
    int gid = blockIdx.x * 256 + threadIdx.x;
    if (gid < 128 * 256) {
        int n = gid >> 8, k = gid & 255;
        float v = (k < 128) ? W2[n * 128 + k] : -W3[n * 128 + (k - 128)];
        Wcat[gid] = f2bfu(v);
    } else {
        int g = gid - 128 * 256;
        W1b[g] = f2bfu(W1[g]);
    }
}

// ---------------- K1: Xb = bf16( [primal|lastp] @ Wcat^T + (b2-b3) )
// block 256 = 4 waves; M-tile 128 (32 rows/wave as 2 groups of 16), N = 128, K = 256 (2 halves).
__global__ __launch_bounds__(256) void k_theta_mfma(
    const float* __restrict__ primal, const float* __restrict__ lastp,
    const short8* __restrict__ Wcat,          // [128][256] bf16 = [128][32] short8
    const float* __restrict__ b2, const float* __restrict__ b3,
    unsigned short* __restrict__ Xb, int nvars)
{
    __shared__ short8 Blds[2048];             // 32 KB: one K-half in fragment order
    const int t = threadIdx.x;
    const int l = t & 63, wv = t >> 6;
    const long mbase = (long)blockIdx.x * 128;

    const f32x4 z = {0.f, 0.f, 0.f, 0.f};
    f32x4 acc[2][8];
    #pragma unroll
    for (int rg = 0; rg < 2; ++rg)
        #pragma unroll
        for (int nb = 0; nb < 8; ++nb) acc[rg][nb] = z;

    for (int half = 0; half < 2; ++half) {
        if (half) __syncthreads();            // finish reads of previous half
        // stage B-half into LDS, pre-arranged in fragment order: entry (nb,ks,lane)
        #pragma unroll
        for (int i = 0; i < 8; ++i) {
            int e = t + i * 256;
            int lane = e & 63, ks = (e >> 6) & 3, nb = e >> 8;
            int row = nb * 16 + (lane & 15);
            int col8 = (half * 128 + ks * 32 + ((lane >> 4) << 3)) >> 3;
            Blds[e] = Wcat[row * 32 + col8];
        }
        __syncthreads();

        const float* Ap = half ? lastp : primal;
        for (int ks = 0; ks < 4; ++ks) {
            short8 af[2];
            #pragma unroll
            for (int rg = 0; rg < 2; ++rg) {
                long row = mbase + wv * 32 + rg * 16 + (l & 15);
                float4 x0 = {0, 0, 0, 0}, x1 = {0, 0, 0, 0};
                if (row < nvars) {
                    const float4* s = (const float4*)(Ap + row * HID + ks * 32 + ((l >> 4) << 3));
                    x0 = s[0]; x1 = s[1];
                }
                af[rg][0] = (short)f2bfu(x0.x); af[rg][1] = (short)f2bfu(x0.y);
                af[rg][2] = (short)f2bfu(x0.z); af[rg][3] = (short)f2bfu(x0.w);
                af[rg][4] = (short)f2bfu(x1.x); af[rg][5] = (short)f2bfu(x1.y);
                af[rg][6] = (short)f2bfu(x1.z); af[rg][7] = (short)f2bfu(x1.w);
            }
            #pragma unroll
            for (int nb = 0; nb < 8; ++nb) {
                short8 bv = Blds[(nb * 4 + ks) * 64 + l];
                MFMA16(acc[0][nb], af[0], bv);
                MFMA16(acc[1][nb], af[1], bv);
            }
        }
    }
    asm volatile("s_nop 7\ns_nop 7");          // MFMA->VALU read hazard insurance

    // epilogue: add bias, convert to bf16, store. C/D: col = l&15, row = (l>>4)*4 + q  [m89/m91]
    #pragma unroll
    for (int nb = 0; nb < 8; ++nb) {
        int col = nb * 16 + (l & 15);
        float bb = b2[col] - b3[col];
        #pragma unroll
        for (int rg = 0; rg < 2; ++rg) {
            #pragma unroll
            for (int q = 0; q < 4; ++q) {
                long row = mbase + wv * 32 + rg * 16 + ((l >> 4) * 4 + q);
                if (row < nvars) Xb[row * HID + col] = f2bfu(acc[rg][nb][q] + bb);
            }
        }
    }
}

// ---------------- CSR build ----------------
__global__ __launch_bounds__(256) void k_count(
    const int* __restrict__ rows, int* __restrict__ count, int nnz)
{
    int e = blockIdx.x * 256 + threadIdx.x;
    if (e < nnz) atomicAdd(&count[rows[e]], 1);
}

__global__ __launch_bounds__(256) void k_scan1(
    const int* __restrict__ count, int* __restrict__ bsum, int m)
{
    __shared__ int red[256];
    int b = blockIdx.x, t = threadIdx.x;
    int base = b * 1024 + t * 4;
    int s = 0;
    #pragma unroll
    for (int i = 0; i < 4; ++i) { int idx = base + i; if (idx < m) s += count[idx]; }
    red[t] = s; __syncthreads();
    for (int off = 128; off > 0; off >>= 1) {
        if (t < off) red[t] += red[t + off];
        __syncthreads();
    }
    if (t == 0) bsum[b] = red[0];
}

__global__ void k_scan2(const int* __restrict__ bsum, int* __restrict__ boff, int nchunks)
{
    if (threadIdx.x == 0 && blockIdx.x == 0) {
        int run = 0;
        for (int i = 0; i < nchunks; ++i) { boff[i] = run; run += bsum[i]; }
    }
}

__global__ __launch_bounds__(256) void k_scan3(
    const int* __restrict__ count, const int* __restrict__ boff,
    int* __restrict__ rowstart, int* __restrict__ cursor, int m)
{
    __shared__ int tsum[256];
    int b = blockIdx.x, t = threadIdx.x;
    int base = b * 1024 + t * 4;
    int v[4]; int s = 0;
    #pragma unroll
    for (int i = 0; i < 4; ++i) { int idx = base + i; v[i] = (idx < m) ? count[idx] : 0; s += v[i]; }
    tsum[t] = s; __syncthreads();
    for (int off = 1; off < 256; off <<= 1) {
        int x = (t >= off) ? tsum[t - off] : 0;
        __syncthreads();
        tsum[t] += x;
        __syncthreads();
    }
    int run = tsum[t] - s + boff[b];
    #pragma unroll
    for (int i = 0; i < 4; ++i) {
        int idx = base + i;
        if (idx < m) { rowstart[idx] = run; cursor[idx] = run; run += v[i]; }
    }
}

__global__ __launch_bounds__(256) void k_fill(
    const int* __restrict__ rows, const int* __restrict__ cols, const float* __restrict__ vals,
    int* __restrict__ cursor, int2* __restrict__ pairs, int nnz)
{
    int e = blockIdx.x * 256 + threadIdx.x;
    if (e >= nnz) return;
    int r = rows[e];
    int slot = atomicAdd(&cursor[r], 1);
    int2 p; p.x = cols[e]; p.y = __float_as_int(vals[e]);
    pairs[slot] = p;
}

// ---------------- K3: out[r,:] = sigma * sum_j val_j * X[col_j,:]   (one wave per row)
// unroll-4: 4 independent pair loads then 4 independent 256B row gathers in flight
__global__ __launch_bounds__(256) void k_segsum(
    const int2* __restrict__ pairs, const int* __restrict__ rowstart, const int* __restrict__ count,
    const unsigned short* __restrict__ Xb, const float* __restrict__ sigp,
    float* __restrict__ out, int m)
{
    int wid = (blockIdx.x * 256 + threadIdx.x) >> 6;
    if (wid >= m) return;
    int lane = threadIdx.x & 63;
    int start = rowstart[wid];
    int cnt   = count[wid];
    const unsigned short* xb = Xb + lane * 2;

    float a0 = 0.f, a1 = 0.f;
    int j = 0;
    for (; j + 4 <= cnt; j += 4) {
        int2 p0 = pairs[start + j + 0];
        int2 p1 = pairs[start + j + 1];
        int2 p2 = pairs[start + j + 2];
        int2 p3 = pairs[start + j + 3];
        unsigned x0 = *(const unsigned*)(xb + (size_t)p0.x * HID);
        unsigned x1 = *(const unsigned*)(xb + (size_t)p1.x * HID);
        unsigned x2 = *(const unsigned*)(xb + (size_t)p2.x * HID);
        unsigned x3 = *(const unsigned*)(xb + (size_t)p3.x * HID);
        float v0 = __int_as_float(p0.y), v1 = __int_as_float(p1.y);
        float v2 = __int_as_float(p2.y), v3 = __int_as_float(p3.y);
        a0 += v0 * bf2f_lo(x0); a1 += v0 * bf2f_hi(x0);
        a0 += v1 * bf2f_lo(x1); a1 += v1 * bf2f_hi(x1);
        a0 += v2 * bf2f_lo(x2); a1 += v2 * bf2f_hi(x2);
        a0 += v3 * bf2f_lo(x3); a1 += v3 * bf2f_hi(x3);
    }
    for (; j < cnt; ++j) {
        int2 p = pairs[start + j];
        float v = __int_as_float(p.y);
        unsigned x = *(const unsigned*)(xb + (size_t)p.x * HID);
        a0 += v * bf2f_lo(x);
        a1 += v * bf2f_hi(x);
    }
    float sg = *sigp;
    ((float2*)out)[(size_t)wid * 64 + lane] = make_float2(sg * a0, sg * a1);
}

// ---------------- K4: out = leaky_relu(dual @ W1^T + b1 + out - sigma*rhs)   (out holds sigma*AX)
__global__ __launch_bounds__(256) void k_dual_mfma(
    const float* __restrict__ dual,
    const short8* __restrict__ W1b,           // [128][128] bf16 = [128][16] short8
    const float* __restrict__ b1, const float* __restrict__ rhs,
    const float* __restrict__ sigp, float* __restrict__ out, int mcons)
{
    __shared__ short8 Blds[2048];             // full W1: 2048 short8 = 128x128 bf16
    const int t = threadIdx.x;
    const int l = t & 63, wv = t >> 6;
    const long mbase = (long)blockIdx.x * 128;
    const float sigma = *sigp;

    const f32x4 z = {0.f, 0.f, 0.f, 0.f};
    f32x4 acc[2][8];
    #pragma unroll
    for (int rg = 0; rg < 2; ++rg)
        #pragma unroll
        for (int nb = 0; nb < 8; ++nb) acc[rg][nb] = z;

    // stage W1 (K=128): ALL 2048 entries (nb<8, ks<4, lane<64)
    #pragma unroll
    for (int i = 0; i < 8; ++i) {
        int e = t + i * 256;
        int lane = e & 63, ks = (e >> 6) & 3, nb = e >> 8;
        int row = nb * 16 + (lane & 15);
        int col8 = (ks * 32 + ((lane >> 4) << 3)) >> 3;
        Blds[e] = W1b[row * 16 + col8];
    }
    __syncthreads();

    for (int ks = 0; ks < 4; ++ks) {
        short8 af[2];
        #pragma unroll
        for (int rg = 0; rg < 2; ++rg) {
            long row = mbase + wv * 32 + rg * 16 + (l & 15);
            float4 x0 = {0, 0, 0, 0}, x1 = {0, 0, 0, 0};
            if (row < mcons) {
                const float4* s = (const float4*)(dual + row * HID + ks * 32 + ((l >> 4) << 3));
                x0 = s[0]; x1 = s[1];
            }
            af[rg][0] = (short)f2bfu(x0.x); af[rg][1] = (short)f2bfu(x0.y);
            af[rg][2] = (short)f2bfu(x0.z); af[rg][3] = (short)f2bfu(x0.w);
            af[rg][4] = (short)f2bfu(x1.x); af[rg][5] = (short)f2bfu(x1.y);
            af[rg][6] = (short)f2bfu(x1.z); af[rg][7] = (short)f2bfu(x1.w);
        }
        #pragma unroll
        for (int nb = 0; nb < 8; ++nb) {
            short8 bv = Blds[(nb * 4 + ks) * 64 + l];
            MFMA16(acc[0][nb], af[0], bv);
            MFMA16(acc[1][nb], af[1], bv);
        }
    }
    asm volatile("s_nop 7\ns_nop 7");          // MFMA->VALU read hazard insurance

    #pragma unroll
    for (int nb = 0; nb < 8; ++nb) {
        int col = nb * 16 + (l & 15);
        float bb = b1[col];
        #pragma unroll
        for (int rg = 0; rg < 2; ++rg) {
            #pragma unroll
            for (int q = 0; q < 4; ++q) {
                long row = mbase + wv * 32 + rg * 16 + ((l >> 4) * 4 + q);
                if (row < mcons) {
                    long idx = row * HID + col;
                    float pre = acc[rg][nb][q] + bb + out[idx] - sigma * rhs[idx];
                    out[idx] = (pre >= 0.f) ? pre : NEG_SLOPE * pre;
                }
            }
        }
    }
}

extern "C" void kernel_launch(void* const* d_in, const int* in_sizes, int n_in,
                              void* d_out, int out_size, void* d_ws, size_t ws_size,
                              hipStream_t stream) {
    const float* primal = (const float*)d_in[0];
    const float* lastp  = (const float*)d_in[1];
    const float* dual   = (const float*)d_in[2];
    const int*   rows   = (const int*)d_in[3];
    const int*   cols   = (const int*)d_in[4];
    const float* vals   = (const float*)d_in[5];
    const float* rhs    = (const float*)d_in[6];
    const float* W1     = (const float*)d_in[7];
    const float* b1     = (const float*)d_in[8];
    const float* W2     = (const float*)d_in[9];
    const float* b2     = (const float*)d_in[10];
    const float* W3     = (const float*)d_in[11];
    const float* b3     = (const float*)d_in[12];
    const float* sigp   = (const float*)d_in[13];

    const int nvars = in_sizes[0] / HID;   // 200000
    const int mcons = in_sizes[2] / HID;   // 100000
    const int nnz   = in_sizes[3];         // 1600000

    float* out = (float*)d_out;

    // ---- workspace layout ----
    char* wsb = (char*)d_ws;
    unsigned short* Xb   = (unsigned short*)wsb;                       // 51.2 MB bf16
    size_t off = (size_t)nvars * HID * sizeof(unsigned short);
    int2* pairs          = (int2*)(wsb + off); off += (size_t)nnz * sizeof(int2);   // 12.8 MB
    unsigned short* Wcat = (unsigned short*)(wsb + off); off += 128 * 256 * 2;
    unsigned short* W1b  = (unsigned short*)(wsb + off); off += 128 * 128 * 2;
    int* count    = (int*)(wsb + off); off += (size_t)mcons * sizeof(int);
    int* rowstart = (int*)(wsb + off); off += (size_t)mcons * sizeof(int);
    int* cursor   = (int*)(wsb + off); off += (size_t)mcons * sizeof(int);
    int* bsum     = (int*)(wsb + off); off += 1024 * sizeof(int);
    int* boff     = (int*)(wsb + off); off += 1024 * sizeof(int);

    const int nchunks = (mcons + 1023) / 1024;

    hipMemsetAsync(count, 0, (size_t)mcons * sizeof(int), stream);

    k_prep<<<192, 256, 0, stream>>>(W1, W2, W3, Wcat, W1b);

    k_theta_mfma<<<(nvars + 127) / 128, 256, 0, stream>>>(
        primal, lastp, (const short8*)Wcat, b2, b3, Xb, nvars);

    k_count<<<(nnz + 255) / 256, 256, 0, stream>>>(rows, count, nnz);
    k_scan1<<<nchunks, 256, 0, stream>>>(count, bsum, mcons);
    k_scan2<<<1, 64, 0, stream>>>(bsum, boff, nchunks);
    k_scan3<<<nchunks, 256, 0, stream>>>(count, boff, rowstart, cursor, mcons);
    k_fill<<<(nnz + 255) / 256, 256, 0, stream>>>(rows, cols, vals, cursor, pairs, nnz);

    k_segsum<<<(mcons * 64 + 255) / 256, 256, 0, stream>>>(
        pairs, rowstart, count, Xb, sigp, out, mcons);

    k_dual_mfma<<<(mcons + 127) / 128, 256, 0, stream>>>(
        dual, (const short8*)W1b, b1, rhs, sigp, out, mcons);
}

// Round 6
// 316.064 us; speedup vs baseline: 9.5817x; 1.2748x over previous
//
#include <hip/hip_runtime.h>

#define HID 128
#define NEG_SLOPE 0.01f
#define NB 256          // row buckets
#define CHUNK 2048      // edges per block in bucket pass (8/thread)
#define MAX_RB 512      // max rows per bucket (mcons <= 131072)

typedef __attribute__((ext_vector_type(8))) short short8;
typedef __attribute__((ext_vector_type(4))) float f32x4;

__device__ inline unsigned short f2bfu(float f) {
    unsigned u = __float_as_uint(f);
    u += 0x7fff + ((u >> 16) & 1);          // round-to-nearest-even
    return (unsigned short)(u >> 16);
}
__device__ inline float bf2f_lo(unsigned x) { return __uint_as_float((x & 0xffffu) << 16); }
__device__ inline float bf2f_hi(unsigned x) { return __uint_as_float(x & 0xffff0000u); }

#define MFMA16(accv, av, bv) \
    asm("v_mfma_f32_16x16x32_bf16 %0, %1, %2, %0" : "+v"(accv) : "v"(av), "v"(bv))

// ---------------- K0: pack weights to bf16. Wcat[n][k] = bf16(k<128 ? W2[n][k] : -W3[n][k-128]);
__global__ __launch_bounds__(256) void k_prep(
    const float* __restrict__ W1, const float* __restrict__ W2, const float* __restrict__ W3,
    unsigned short* __restrict__ Wcat, unsigned short* __restrict__ W1b)
{
    int gid = blockIdx.x * 256 + threadIdx.x;
    if (gid < 128 * 256) {
        int n = gid >> 8, k = gid & 255;
        float v = (k < 128) ? W2[n * 128 + k] : -W3[n * 128 + (k - 128)];
        Wcat[gid] = f2bfu(v);
    } else {
        int g = gid - 128 * 256;
        W1b[g] = f2bfu(W1[g]);
    }
}

// ---------------- K1: Xb = bf16( [primal|lastp] @ Wcat^T + (b2-b3) )
__global__ __launch_bounds__(256) void k_theta_mfma(
    const float* __restrict__ primal, const float* __restrict__ lastp,
    const short8* __restrict__ Wcat,          // [128][256] bf16 = [128][32] short8
    const float* __restrict__ b2, const float* __restrict__ b3,
    unsigned short* __restrict__ Xb, int nvars)
{
    __shared__ short8 Blds[2048];             // 32 KB: one K-half in fragment order
    const int t = threadIdx.x;
    const int l = t & 63, wv = t >> 6;
    const long mbase = (long)blockIdx.x * 128;

    const f32x4 z = {0.f, 0.f, 0.f, 0.f};
    f32x4 acc[2][8];
    #pragma unroll
    for (int rg = 0; rg < 2; ++rg)
        #pragma unroll
        for (int nb = 0; nb < 8; ++nb) acc[rg][nb] = z;

    for (int half = 0; half < 2; ++half) {
        if (half) __syncthreads();            // finish reads of previous half
        #pragma unroll
        for (int i = 0; i < 8; ++i) {
            int e = t + i * 256;
            int lane = e & 63, ks = (e >> 6) & 3, nb = e >> 8;
            int row = nb * 16 + (lane & 15);
            int col8 = (half * 128 + ks * 32 + ((lane >> 4) << 3)) >> 3;
            Blds[e] = Wcat[row * 32 + col8];
        }
        __syncthreads();

        const float* Ap = half ? lastp : primal;
        for (int ks = 0; ks < 4; ++ks) {
            short8 af[2];
            #pragma unroll
            for (int rg = 0; rg < 2; ++rg) {
                long row = mbase + wv * 32 + rg * 16 + (l & 15);
                float4 x0 = {0, 0, 0, 0}, x1 = {0, 0, 0, 0};
                if (row < nvars) {
                    const float4* s = (const float4*)(Ap + row * HID + ks * 32 + ((l >> 4) << 3));
                    x0 = s[0]; x1 = s[1];
                }
                af[rg][0] = (short)f2bfu(x0.x); af[rg][1] = (short)f2bfu(x0.y);
                af[rg][2] = (short)f2bfu(x0.z); af[rg][3] = (short)f2bfu(x0.w);
                af[rg][4] = (short)f2bfu(x1.x); af[rg][5] = (short)f2bfu(x1.y);
                af[rg][6] = (short)f2bfu(x1.z); af[rg][7] = (short)f2bfu(x1.w);
            }
            #pragma unroll
            for (int nb = 0; nb < 8; ++nb) {
                short8 bv = Blds[(nb * 4 + ks) * 64 + l];
                MFMA16(acc[0][nb], af[0], bv);
                MFMA16(acc[1][nb], af[1], bv);
            }
        }
    }
    asm volatile("s_nop 7\ns_nop 7");          // MFMA->VALU read hazard insurance

    // C/D: col = l&15, row = (l>>4)*4 + q
    #pragma unroll
    for (int nb = 0; nb < 8; ++nb) {
        int col = nb * 16 + (l & 15);
        float bb = b2[col] - b3[col];
        #pragma unroll
        for (int rg = 0; rg < 2; ++rg) {
            #pragma unroll
            for (int q = 0; q < 4; ++q) {
                long row = mbase + wv * 32 + rg * 16 + ((l >> 4) * 4 + q);
                if (row < nvars) Xb[row * HID + col] = f2bfu(acc[rg][nb][q] + bb);
            }
        }
    }
}

// ---------------- bucket pass A: global bucket histogram
__global__ __launch_bounds__(256) void k_bhist(
    const int* __restrict__ rows, int* __restrict__ bucket_count, int nnz, int rb)
{
    __shared__ int hist[NB];
    int t = threadIdx.x;
    hist[t] = 0; __syncthreads();
    long cbase = (long)blockIdx.x * CHUNK;
    #pragma unroll
    for (int i = 0; i < 8; ++i) {
        long e = cbase + i * 256 + t;
        if (e < nnz) atomicAdd(&hist[rows[e] / rb], 1);
    }
    __syncthreads();
    if (hist[t]) atomicAdd(&bucket_count[t], hist[t]);
}

// ---------------- bucket pass B: scan bucket sizes
__global__ void k_bscan(const int* __restrict__ bucket_count,
                        int* __restrict__ bucket_base, int* __restrict__ bucket_cursor)
{
    if (threadIdx.x == 0 && blockIdx.x == 0) {
        int run = 0;
        for (int i = 0; i < NB; ++i) {
            bucket_base[i] = run; bucket_cursor[i] = run; run += bucket_count[i];
        }
        bucket_base[NB] = run;
    }
}

// ---------------- bucket pass C: bin edges into bucket-contiguous tmp arrays.
// Per-block LDS cursors; each block reserves contiguous per-bucket runs ->
// writes are block-private contiguous runs (single XCD -> ~1x line writeback).
__global__ __launch_bounds__(256) void k_bfill(
    const int* __restrict__ rows, const int* __restrict__ cols, const float* __restrict__ vals,
    int* __restrict__ bucket_cursor, int2* __restrict__ tmp_rc, float* __restrict__ tmp_v,
    int nnz, int rb)
{
    __shared__ int hist[NB];
    __shared__ int base[NB];
    int t = threadIdx.x;
    long cbase = (long)blockIdx.x * CHUNK;
    hist[t] = 0;
    __syncthreads();

    int r[8], c[8], b[8], loc[8];
    float v[8];
    #pragma unroll
    for (int i = 0; i < 8; ++i) {
        long e = cbase + i * 256 + t;
        int locv = -1; int bi = 0; int ri = 0, ci = 0; float vi = 0.f;
        if (e < nnz) {
            ri = rows[e]; ci = cols[e]; vi = vals[e];
            bi = ri / rb;
            locv = atomicAdd(&hist[bi], 1);
        }
        r[i] = ri; c[i] = ci; v[i] = vi; b[i] = bi; loc[i] = locv;
    }
    __syncthreads();
    if (hist[t] > 0) base[t] = atomicAdd(&bucket_cursor[t], hist[t]);
    __syncthreads();
    #pragma unroll
    for (int i = 0; i < 8; ++i) {
        if (loc[i] >= 0) {
            int slot = base[b[i]] + loc[i];
            tmp_rc[slot] = make_int2(r[i], c[i]);
            tmp_v[slot]  = v[i];
        }
    }
}

// ---------------- bucket pass D: one block per bucket -> local CSR + pairs.
// All writes to this bucket's pairs region come from ONE block (one XCD).
__global__ __launch_bounds__(256) void k_csr(
    const int2* __restrict__ tmp_rc, const float* __restrict__ tmp_v,
    const int* __restrict__ bucket_base,
    int* __restrict__ rowstart, int* __restrict__ count, int2* __restrict__ pairs,
    int m, int rb)
{
    __shared__ int cnt[MAX_RB];
    __shared__ int cur[MAX_RB];
    int b = blockIdx.x, t = threadIdx.x;
    int row0 = b * rb;
    int nrows = m - row0; if (nrows > rb) nrows = rb;
    if (nrows <= 0) return;

    for (int i = t; i < nrows; i += 256) cnt[i] = 0;
    __syncthreads();

    int e0 = bucket_base[b], e1 = bucket_base[b + 1];
    for (int e = e0 + t; e < e1; e += 256)
        atomicAdd(&cnt[tmp_rc[e].x - row0], 1);
    __syncthreads();

    if (t == 0) {
        int run = e0;
        for (int i = 0; i < nrows; ++i) { cur[i] = run; run += cnt[i]; }
    }
    __syncthreads();

    for (int i = t; i < nrows; i += 256) {
        rowstart[row0 + i] = cur[i];
        count[row0 + i]    = cnt[i];
    }
    __syncthreads();

    for (int e = e0 + t; e < e1; e += 256) {
        int2 rc = tmp_rc[e];
        float vv = tmp_v[e];
        int slot = atomicAdd(&cur[rc.x - row0], 1);
        pairs[slot] = make_int2(rc.y, __float_as_int(vv));
    }
}

// ---------------- K3: out[r,:] = sigma * sum_j val_j * X[col_j,:]   (one wave per row, unroll-4)
__global__ __launch_bounds__(256) void k_segsum(
    const int2* __restrict__ pairs, const int* __restrict__ rowstart, const int* __restrict__ count,
    const unsigned short* __restrict__ Xb, const float* __restrict__ sigp,
    float* __restrict__ out, int m)
{
    int wid = (blockIdx.x * 256 + threadIdx.x) >> 6;
    if (wid >= m) return;
    int lane = threadIdx.x & 63;
    int start = rowstart[wid];
    int cnt   = count[wid];
    const unsigned short* xb = Xb + lane * 2;

    float a0 = 0.f, a1 = 0.f;
    int j = 0;
    for (; j + 4 <= cnt; j += 4) {
        int2 p0 = pairs[start + j + 0];
        int2 p1 = pairs[start + j + 1];
        int2 p2 = pairs[start + j + 2];
        int2 p3 = pairs[start + j + 3];
        unsigned x0 = *(const unsigned*)(xb + (size_t)p0.x * HID);
        unsigned x1 = *(const unsigned*)(xb + (size_t)p1.x * HID);
        unsigned x2 = *(const unsigned*)(xb + (size_t)p2.x * HID);
        unsigned x3 = *(const unsigned*)(xb + (size_t)p3.x * HID);
        float v0 = __int_as_float(p0.y), v1 = __int_as_float(p1.y);
        float v2 = __int_as_float(p2.y), v3 = __int_as_float(p3.y);
        a0 += v0 * bf2f_lo(x0); a1 += v0 * bf2f_hi(x0);
        a0 += v1 * bf2f_lo(x1); a1 += v1 * bf2f_hi(x1);
        a0 += v2 * bf2f_lo(x2); a1 += v2 * bf2f_hi(x2);
        a0 += v3 * bf2f_lo(x3); a1 += v3 * bf2f_hi(x3);
    }
    for (; j < cnt; ++j) {
        int2 p = pairs[start + j];
        float v = __int_as_float(p.y);
        unsigned x = *(const unsigned*)(xb + (size_t)p.x * HID);
        a0 += v * bf2f_lo(x);
        a1 += v * bf2f_hi(x);
    }
    float sg = *sigp;
    ((float2*)out)[(size_t)wid * 64 + lane] = make_float2(sg * a0, sg * a1);
}

// ---------------- K4: out = leaky_relu(dual @ W1^T + b1 + out - sigma*rhs)
__global__ __launch_bounds__(256) void k_dual_mfma(
    const float* __restrict__ dual,
    const short8* __restrict__ W1b,           // [128][128] bf16 = [128][16] short8
    const float* __restrict__ b1, const float* __restrict__ rhs,
    const float* __restrict__ sigp, float* __restrict__ out, int mcons)
{
    __shared__ short8 Blds[2048];
    const int t = threadIdx.x;
    const int l = t & 63, wv = t >> 6;
    const long mbase = (long)blockIdx.x * 128;
    const float sigma = *sigp;

    const f32x4 z = {0.f, 0.f, 0.f, 0.f};
    f32x4 acc[2][8];
    #pragma unroll
    for (int rg = 0; rg < 2; ++rg)
        #pragma unroll
        for (int nb = 0; nb < 8; ++nb) acc[rg][nb] = z;

    #pragma unroll
    for (int i = 0; i < 8; ++i) {
        int e = t + i * 256;
        int lane = e & 63, ks = (e >> 6) & 3, nb = e >> 8;
        int row = nb * 16 + (lane & 15);
        int col8 = (ks * 32 + ((lane >> 4) << 3)) >> 3;
        Blds[e] = W1b[row * 16 + col8];
    }
    __syncthreads();

    for (int ks = 0; ks < 4; ++ks) {
        short8 af[2];
        #pragma unroll
        for (int rg = 0; rg < 2; ++rg) {
            long row = mbase + wv * 32 + rg * 16 + (l & 15);
            float4 x0 = {0, 0, 0, 0}, x1 = {0, 0, 0, 0};
            if (row < mcons) {
                const float4* s = (const float4*)(dual + row * HID + ks * 32 + ((l >> 4) << 3));
                x0 = s[0]; x1 = s[1];
            }
            af[rg][0] = (short)f2bfu(x0.x); af[rg][1] = (short)f2bfu(x0.y);
            af[rg][2] = (short)f2bfu(x0.z); af[rg][3] = (short)f2bfu(x0.w);
            af[rg][4] = (short)f2bfu(x1.x); af[rg][5] = (short)f2bfu(x1.y);
            af[rg][6] = (short)f2bfu(x1.z); af[rg][7] = (short)f2bfu(x1.w);
        }
        #pragma unroll
        for (int nb = 0; nb < 8; ++nb) {
            short8 bv = Blds[(nb * 4 + ks) * 64 + l];
            MFMA16(acc[0][nb], af[0], bv);
            MFMA16(acc[1][nb], af[1], bv);
        }
    }
    asm volatile("s_nop 7\ns_nop 7");

    #pragma unroll
    for (int nb = 0; nb < 8; ++nb) {
        int col = nb * 16 + (l & 15);
        float bb = b1[col];
        #pragma unroll
        for (int rg = 0; rg < 2; ++rg) {
            #pragma unroll
            for (int q = 0; q < 4; ++q) {
                long row = mbase + wv * 32 + rg * 16 + ((l >> 4) * 4 + q);
                if (row < mcons) {
                    long idx = row * HID + col;
                    float pre = acc[rg][nb][q] + bb + out[idx] - sigma * rhs[idx];
                    out[idx] = (pre >= 0.f) ? pre : NEG_SLOPE * pre;
                }
            }
        }
    }
}

extern "C" void kernel_launch(void* const* d_in, const int* in_sizes, int n_in,
                              void* d_out, int out_size, void* d_ws, size_t ws_size,
                              hipStream_t stream) {
    const float* primal = (const float*)d_in[0];
    const float* lastp  = (const float*)d_in[1];
    const float* dual   = (const float*)d_in[2];
    const int*   rows   = (const int*)d_in[3];
    const int*   cols   = (const int*)d_in[4];
    const float* vals   = (const float*)d_in[5];
    const float* rhs    = (const float*)d_in[6];
    const float* W1     = (const float*)d_in[7];
    const float* b1     = (const float*)d_in[8];
    const float* W2     = (const float*)d_in[9];
    const float* b2     = (const float*)d_in[10];
    const float* W3     = (const float*)d_in[11];
    const float* b3     = (const float*)d_in[12];
    const float* sigp   = (const float*)d_in[13];

    const int nvars = in_sizes[0] / HID;   // 200000
    const int mcons = in_sizes[2] / HID;   // 100000
    const int nnz   = in_sizes[3];         // 1600000
    const int rb    = (mcons + NB - 1) / NB;   // rows per bucket (391)

    float* out = (float*)d_out;

    // ---- workspace layout ----
    char* wsb = (char*)d_ws;
    unsigned short* Xb   = (unsigned short*)wsb;                        // 51.2 MB bf16
    size_t off = (size_t)nvars * HID * sizeof(unsigned short);
    int2* pairs   = (int2*)(wsb + off);  off += (size_t)nnz * sizeof(int2);   // 12.8 MB
    int2* tmp_rc  = (int2*)(wsb + off);  off += (size_t)nnz * sizeof(int2);   // 12.8 MB
    float* tmp_v  = (float*)(wsb + off); off += (size_t)nnz * sizeof(float);  //  6.4 MB
    unsigned short* Wcat = (unsigned short*)(wsb + off); off += 128 * 256 * 2;
    unsigned short* W1b  = (unsigned short*)(wsb + off); off += 128 * 128 * 2;
    int* count         = (int*)(wsb + off); off += (size_t)mcons * sizeof(int);
    int* rowstart      = (int*)(wsb + off); off += (size_t)mcons * sizeof(int);
    int* bucket_count  = (int*)(wsb + off); off += NB * sizeof(int);
    int* bucket_base   = (int*)(wsb + off); off += (NB + 1) * sizeof(int);
    int* bucket_cursor = (int*)(wsb + off); off += NB * sizeof(int);

    hipMemsetAsync(bucket_count, 0, NB * sizeof(int), stream);

    k_prep<<<192, 256, 0, stream>>>(W1, W2, W3, Wcat, W1b);

    const int nchunk_blocks = (nnz + CHUNK - 1) / CHUNK;
    k_bhist<<<nchunk_blocks, 256, 0, stream>>>(rows, bucket_count, nnz, rb);
    k_bscan<<<1, 64, 0, stream>>>(bucket_count, bucket_base, bucket_cursor);
    k_bfill<<<nchunk_blocks, 256, 0, stream>>>(rows, cols, vals, bucket_cursor,
                                               tmp_rc, tmp_v, nnz, rb);
    k_csr<<<NB, 256, 0, stream>>>(tmp_rc, tmp_v, bucket_base,
                                  rowstart, count, pairs, mcons, rb);

    k_theta_mfma<<<(nvars + 127) / 128, 256, 0, stream>>>(
        primal, lastp, (const short8*)Wcat, b2, b3, Xb, nvars);

    k_segsum<<<(mcons * 64 + 255) / 256, 256, 0, stream>>>(
        pairs, rowstart, count, Xb, sigp, out, mcons);

    k_dual_mfma<<<(mcons + 127) / 128, 256, 0, stream>>>(
        dual, (const short8*)W1b, b1, rhs, sigp, out, mcons);
}